// Round 2
// 349.218 us; speedup vs baseline: 1.0166x; 1.0166x over previous
//
#include <hip/hip_runtime.h>

// cdist(x1, x2) on MI355X: d[i][j] = sqrt(||x1_i||^2 + ||x2_j||^2 - 2*x1_i.x2_j)
// fp32->bf16 convert + fp32 row norms (prologue), then bf16 MFMA GEMM with
// fused sqrt epilogue.
// R2 = R1 resubmit (container failure attributed to infra after source audit:
// no OOB, bijective block map, uniform barriers, 128 KiB LDS precedented by
// the verified 8-phase 256^2 template). Only change: drop min-waves arg from
// __launch_bounds__ (128 KiB LDS pins occupancy at 1 block/CU anyway).
// R1: 256x256 tile, 8 waves (2x4), BK=64, double-buffered LDS (128 KiB),
// global_load_lds width=16, XCD-aware 2D block chunking, nontemporal C-stores.
// Rationale: K=256 -> only 4 K-steps/block; the 128^2 tile paid prologue+
// barrier-drain+epilogue for ~no compute (245 eff TF). Bigger tile + dbuf
// overlap targets the ~60us overlapped write/compute floor.

typedef __bf16 v8bf __attribute__((ext_vector_type(8)));
typedef float v4f __attribute__((ext_vector_type(4)));

#define NROWS 8192
#define KDIM  256
#define BM    256
#define BN    256
#define BK    64
#define NTHREADS 512

typedef const __attribute__((address_space(1))) ushort* gas_ushort_p;
typedef __attribute__((address_space(3))) ushort* las_ushort_p;

__device__ __forceinline__ void async_load16(const ushort* g, ushort* l) {
    // global -> LDS direct DMA, 16B per lane. LDS dest is wave-uniform base +
    // lane*16 (hardware uses first lane's lds address).
    __builtin_amdgcn_global_load_lds((gas_ushort_p)g, (las_ushort_p)l, 16, 0, 0);
}

__device__ __forceinline__ ushort f2bf_rne(float f) {
    union { float f; unsigned u; } a; a.f = f;
    unsigned u = a.u + 0x7fffu + ((a.u >> 16) & 1u);  // round-to-nearest-even
    return (ushort)(u >> 16);
}

// One wave per row: load 256 floats as float4/lane, emit bf16 row + fp32 norm.
__global__ __launch_bounds__(256) void cvt_norm_kernel(
    const float* __restrict__ x, ushort* __restrict__ xb, float* __restrict__ sq) {
    const int wave = threadIdx.x >> 6;
    const int lane = threadIdx.x & 63;
    const int row  = blockIdx.x * 4 + wave;
    const float4 v = ((const float4*)(x + (size_t)row * KDIM))[lane];
    float s = v.x * v.x + v.y * v.y + v.z * v.z + v.w * v.w;
#pragma unroll
    for (int off = 32; off; off >>= 1) s += __shfl_down(s, off);
    if (lane == 0) sq[row] = s;
    ushort4 o;
    o.x = f2bf_rne(v.x); o.y = f2bf_rne(v.y);
    o.z = f2bf_rne(v.z); o.w = f2bf_rne(v.w);
    ((ushort4*)(xb + (size_t)row * KDIM))[lane] = o;
}

__global__ __launch_bounds__(NTHREADS) void cdist_mfma_kernel(
    const ushort* __restrict__ A,    // x1 bf16, [8192][256]
    const ushort* __restrict__ B,    // x2 bf16, [8192][256]
    const float* __restrict__ sq1,   // ||x1_i||^2
    const float* __restrict__ sq2,   // ||x2_j||^2
    float* __restrict__ out) {       // [8192][8192]
    // Double-buffered tiles: 2 x (256x64 bf16) x 2 matrices = 128 KiB LDS.
    __shared__ ushort As[2][BM * BK];
    __shared__ ushort Bs[2][BN * BK];

    // XCD-aware 2D chunking: 1024 blocks -> 8 XCD chunks of 16(bm) x 8(bn).
    // Consecutive blockIdx round-robins XCDs; each XCD walks its own chunk
    // (working set: A 2MB + B 1MB < 4MB per-XCD L2).
    const int bid = blockIdx.x;
    const int xcd = bid & 7;
    const int cc  = bid >> 3;                        // 0..127 within chunk
    const int bm  = ((xcd >> 2) << 4) + (cc >> 3);   // 0..31
    const int bn  = ((xcd & 3) << 3) + (cc & 7);     // 0..31

    const int tid  = threadIdx.x;
    const int wave = tid >> 6;
    const int lane = tid & 63;
    const int wr = wave >> 2;         // wave tile row (0..1) -> 128 rows
    const int wc = wave & 3;          // wave tile col (0..3) -> 64 cols

    // staging lane layout: 8 lanes x 16B cover one 64-elem bf16 row (128 B)
    const int lrow = lane >> 3;       // 0..7 rows within an 8-row chunk
    const int lk   = (lane & 7) * 8;  // bf16 k-offset within row

    const int half = lane >> 4;       // 0..3
    const int mrow = lane & 15;       // fragment row/col within 16

    const int rowA = bm * BM;
    const int rowB = bn * BN;

    v4f acc[8][4];
#pragma unroll
    for (int i = 0; i < 8; ++i)
#pragma unroll
        for (int j = 0; j < 4; ++j) acc[i][j] = (v4f){0.f, 0.f, 0.f, 0.f};

    // Each wave stages 32 rows of A and 32 rows of B per K-step (4 calls x 8 rows).
    auto stage = [&](int buf, int kt) {
#pragma unroll
        for (int c = 0; c < 4; ++c) {
            const int rbase = wave * 32 + c * 8;
            async_load16(A + (size_t)(rowA + rbase + lrow) * KDIM + kt + lk,
                         &As[buf][rbase * BK]);
            async_load16(B + (size_t)(rowB + rbase + lrow) * KDIM + kt + lk,
                         &Bs[buf][rbase * BK]);
        }
    };

    auto compute = [&](int buf) {
#pragma unroll
        for (int kk = 0; kk < BK; kk += 32) {
            v8bf a[8], b[4];
#pragma unroll
            for (int i = 0; i < 8; ++i)
                a[i] = *(const v8bf*)&As[buf][(wr * 128 + i * 16 + mrow) * BK + kk + half * 8];
#pragma unroll
            for (int j = 0; j < 4; ++j)
                b[j] = *(const v8bf*)&Bs[buf][(wc * 64 + j * 16 + mrow) * BK + kk + half * 8];
#pragma unroll
            for (int i = 0; i < 8; ++i)
#pragma unroll
                for (int j = 0; j < 4; ++j)
                    acc[i][j] = __builtin_amdgcn_mfma_f32_16x16x32_bf16(
                        a[i], b[j], acc[i][j], 0, 0, 0);
        }
    };

    // 2-phase double-buffered pipeline: stage(t+1) issues before compute(t);
    // __syncthreads() (compiler-inserted vmcnt/lgkmcnt drain) fences the flip.
    stage(0, 0);
    __syncthreads();
    int cur = 0;
#pragma unroll
    for (int t = 0; t < KDIM / BK - 1; ++t) {
        stage(cur ^ 1, (t + 1) * BK);   // next tile loads fly under compute
        compute(cur);
        __syncthreads();
        cur ^= 1;
    }
    compute(cur);

    // Epilogue: C/D layout col=lane&15, row=(lane>>4)*4+reg (m89/m91 verified).
    // Nontemporal stores: output is write-once, keep A/B resident in L2.
    const int m0 = rowA + wr * 128;
    const int n0 = rowB + wc * 64;
    float s2v[4];
#pragma unroll
    for (int j = 0; j < 4; ++j) s2v[j] = sq2[n0 + j * 16 + mrow];
#pragma unroll
    for (int i = 0; i < 8; ++i) {
        const int rbase = m0 + i * 16 + half * 4;
        float s1v[4];
#pragma unroll
        for (int r = 0; r < 4; ++r) s1v[r] = sq1[rbase + r];
#pragma unroll
        for (int r = 0; r < 4; ++r) {
            float* op = out + (size_t)(rbase + r) * NROWS + n0 + mrow;
#pragma unroll
            for (int j = 0; j < 4; ++j) {
                const float d2 = s1v[r] + s2v[j] - 2.0f * acc[i][j][r];
                __builtin_nontemporal_store(sqrtf(fmaxf(d2, 0.0f)), op + j * 16);
            }
        }
    }
}

extern "C" void kernel_launch(void* const* d_in, const int* in_sizes, int n_in,
                              void* d_out, int out_size, void* d_ws, size_t ws_size,
                              hipStream_t stream) {
    const float* x1 = (const float*)d_in[0];
    const float* x2 = (const float*)d_in[1];
    float* out = (float*)d_out;

    // ws layout: A_bf16 (4 MiB) | B_bf16 (4 MiB) | sq1 (32 KiB) | sq2 (32 KiB)
    ushort* Ab = (ushort*)d_ws;
    ushort* Bb = Ab + (size_t)NROWS * KDIM;
    float* sq1 = (float*)(Bb + (size_t)NROWS * KDIM);
    float* sq2 = sq1 + NROWS;

    cvt_norm_kernel<<<NROWS / 4, 256, 0, stream>>>(x1, Ab, sq1);
    cvt_norm_kernel<<<NROWS / 4, 256, 0, stream>>>(x2, Bb, sq2);

    // 32x32 = 1024 blocks, XCD-chunked inside the kernel.
    cdist_mfma_kernel<<<1024, NTHREADS, 0, stream>>>(Ab, Bb, sq1, sq2, out);
}